// Round 4
// baseline (859.023 us; speedup 1.0000x reference)
//
#include <hip/hip_runtime.h>
#include <math.h>

#define BB 4096
#define HH 2048
#define NBK 4
#define HB 512

typedef short bh8 __attribute__((ext_vector_type(8)));
typedef float f32x4 __attribute__((ext_vector_type(4)));

__device__ __forceinline__ float gelu_exact(float v) {
    return 0.5f * v * (1.0f + erff(v * 0.70710678118654752f));
}

// Convert 8 fp32 -> 8 bf16 hi (truncate) + 8 bf16 lo (residual, truncate),
// write 16B each into swizzled LDS slots.
__device__ __forceinline__ void cvt_store(char* hiB, char* loB, int row, int cb,
                                          float4 f0, float4 f1) {
    unsigned u0 = __float_as_uint(f0.x), u1 = __float_as_uint(f0.y),
             u2 = __float_as_uint(f0.z), u3 = __float_as_uint(f0.w),
             u4 = __float_as_uint(f1.x), u5 = __float_as_uint(f1.y),
             u6 = __float_as_uint(f1.z), u7 = __float_as_uint(f1.w);
    uint4 H;
    H.x = (u1 & 0xFFFF0000u) | (u0 >> 16);
    H.y = (u3 & 0xFFFF0000u) | (u2 >> 16);
    H.z = (u5 & 0xFFFF0000u) | (u4 >> 16);
    H.w = (u7 & 0xFFFF0000u) | (u6 >> 16);
    float l0 = f0.x - __uint_as_float(u0 & 0xFFFF0000u);
    float l1 = f0.y - __uint_as_float(u1 & 0xFFFF0000u);
    float l2 = f0.z - __uint_as_float(u2 & 0xFFFF0000u);
    float l3 = f0.w - __uint_as_float(u3 & 0xFFFF0000u);
    float l4 = f1.x - __uint_as_float(u4 & 0xFFFF0000u);
    float l5 = f1.y - __uint_as_float(u5 & 0xFFFF0000u);
    float l6 = f1.z - __uint_as_float(u6 & 0xFFFF0000u);
    float l7 = f1.w - __uint_as_float(u7 & 0xFFFF0000u);
    unsigned v0 = __float_as_uint(l0), v1 = __float_as_uint(l1),
             v2 = __float_as_uint(l2), v3 = __float_as_uint(l3),
             v4 = __float_as_uint(l4), v5 = __float_as_uint(l5),
             v6 = __float_as_uint(l6), v7 = __float_as_uint(l7);
    uint4 L;
    L.x = (v1 & 0xFFFF0000u) | (v0 >> 16);
    L.y = (v3 & 0xFFFF0000u) | (v2 >> 16);
    L.z = (v5 & 0xFFFF0000u) | (v4 >> 16);
    L.w = (v7 & 0xFFFF0000u) | (v6 >> 16);
    const int s = (cb ^ ((row >> 1) & 3)) * 16;   // XOR swizzle of 16B slot
    *(uint4*)(hiB + row * 64 + s) = H;
    *(uint4*)(loB + row * 64 + s) = L;
}

// C[M,N] = A[M,K] @ B[N,K]^T via split-bf16 MFMA: AhBh + AhBl + AlBh.
// 128x128 tile, BK=32, 4 waves (2x2 of 64x64). Double-buffered LDS,
// ONE barrier per K-tile: loads issued top, MFMAs middle, cvt_store of
// next tile bottom -> conversion VALU overlaps MFMA via wave skew.
template<int EPI>
__global__ __launch_bounds__(256, 2)
void bgemm_bt(const float* __restrict__ A, int lda, long batchA,
              const float* __restrict__ Bm, int ldb, long batchB,
              float* __restrict__ C, int ldc, long batchC, int K)
{
    constexpr int BK = 32;
    __shared__ uint4 ldsv[4096];                 // 64 KB: 2 x {Ah,Al,Bh,Bl}
    char* lds = (char*)ldsv;

    A  += (long)blockIdx.z * batchA;
    Bm += (long)blockIdx.z * batchB;
    C  += (long)blockIdx.z * batchC;

    const int tid  = threadIdx.x;
    const int row0 = blockIdx.y * 128;
    const int col0 = blockIdx.x * 128;

    const int sr  = tid >> 2;
    const int scb = tid & 3;
    const float* Ald = A  + (long)(row0 + sr) * lda + scb * 8;
    const float* Bld = Bm + (long)(col0 + sr) * ldb + scb * 8;
    const long a64 = 64L * lda, b64 = 64L * ldb;

    const int lane = tid & 63;
    const int wr = (tid >> 7) & 1;
    const int wc = (tid >> 6) & 1;
    const int fm = lane & 15;
    const int kb = lane >> 4;
    const int slot = ((kb ^ ((fm >> 1) & 3)) & 3) * 16;
    const int aoff = (wr * 64 + fm) * 64 + slot;
    const int boff = (wc * 64 + fm) * 64 + slot;

    f32x4 acc[4][4] = {};

    float4 p0, p1, p2, p3, p4, p5, p6, p7;
    p0 = *(const float4*)(Ald);         p1 = *(const float4*)(Ald + 4);
    p2 = *(const float4*)(Ald + a64);   p3 = *(const float4*)(Ald + a64 + 4);
    p4 = *(const float4*)(Bld);         p5 = *(const float4*)(Bld + 4);
    p6 = *(const float4*)(Bld + b64);   p7 = *(const float4*)(Bld + b64 + 4);
    cvt_store(lds,         lds + 8192,  sr,      scb, p0, p1);
    cvt_store(lds,         lds + 8192,  sr + 64, scb, p2, p3);
    cvt_store(lds + 16384, lds + 24576, sr,      scb, p4, p5);
    cvt_store(lds + 16384, lds + 24576, sr + 64, scb, p6, p7);
    __syncthreads();

    const int nkt = K / BK;
    for (int kt = 0; kt < nkt; ++kt) {
        const int cur = (kt & 1) << 15;
        const int nxt = cur ^ 32768;
        if (kt + 1 < nkt) {                       // issue next-tile loads early
            const float* pa = Ald + (kt + 1) * BK;
            const float* pb = Bld + (kt + 1) * BK;
            p0 = *(const float4*)(pa);         p1 = *(const float4*)(pa + 4);
            p2 = *(const float4*)(pa + a64);   p3 = *(const float4*)(pa + a64 + 4);
            p4 = *(const float4*)(pb);         p5 = *(const float4*)(pb + 4);
            p6 = *(const float4*)(pb + b64);   p7 = *(const float4*)(pb + b64 + 4);
        }
        char* Ah = lds + cur;          char* Al = Ah + 8192;
        char* Bh = lds + cur + 16384;  char* Bl = Bh + 8192;
        bh8 ahf[4], alf[4];
        #pragma unroll
        for (int i = 0; i < 4; ++i) {
            ahf[i] = *(const bh8*)(Ah + aoff + i * 1024);
            alf[i] = *(const bh8*)(Al + aoff + i * 1024);
        }
        #pragma unroll
        for (int j = 0; j < 4; ++j) {
            const bh8 bhf = *(const bh8*)(Bh + boff + j * 1024);
            const bh8 blf = *(const bh8*)(Bl + boff + j * 1024);
            #pragma unroll
            for (int i = 0; i < 4; ++i)
                acc[i][j] = __builtin_amdgcn_mfma_f32_16x16x32_bf16(ahf[i], bhf, acc[i][j], 0, 0, 0);
            #pragma unroll
            for (int i = 0; i < 4; ++i)
                acc[i][j] = __builtin_amdgcn_mfma_f32_16x16x32_bf16(ahf[i], blf, acc[i][j], 0, 0, 0);
            #pragma unroll
            for (int i = 0; i < 4; ++i)
                acc[i][j] = __builtin_amdgcn_mfma_f32_16x16x32_bf16(alf[i], bhf, acc[i][j], 0, 0, 0);
        }
        if (kt + 1 < nkt) {                       // store next tile into other buf
            cvt_store(lds + nxt,         lds + nxt + 8192,  sr,      scb, p0, p1);
            cvt_store(lds + nxt,         lds + nxt + 8192,  sr + 64, scb, p2, p3);
            cvt_store(lds + nxt + 16384, lds + nxt + 24576, sr,      scb, p4, p5);
            cvt_store(lds + nxt + 16384, lds + nxt + 24576, sr + 64, scb, p6, p7);
        }
        __syncthreads();
    }

    // D col = lane&15, row = (lane>>4)*4 + reg (verified m89 layout)
    const int erow = row0 + wr * 64 + (lane >> 4) * 4;
    const int ecol = col0 + wc * 64 + fm;
    #pragma unroll
    for (int i = 0; i < 4; ++i)
        #pragma unroll
        for (int j = 0; j < 4; ++j)
            #pragma unroll
            for (int r = 0; r < 4; ++r) {
                float v = acc[i][j][r];
                if (EPI == 1) v = gelu_exact(v);
                C[(long)(erow + i * 16 + r) * ldc + ecol + j * 16] = v;
            }
}

// Fused: yi = blockdiag(xc,Wi), yr = blockdiag(xc,Wrg), then full RG-LRU
// elementwise in the epilogue. Writes nrs (d_out) and h = gate*nrs (ws).
// Grid: (HB/128, BB/128, NBK).
__global__ __launch_bounds__(256, 2)
void bd_rglru(const float* __restrict__ xc,
              const float* __restrict__ Wi,
              const float* __restrict__ Wrg,
              const float* __restrict__ rg,
              const float* __restrict__ gate,
              const float* __restrict__ av,
              float* __restrict__ nrs,
              float* __restrict__ hbuf)
{
    constexpr int BK = 32;
    __shared__ uint4 ldsv[3072];                 // 48 KB
    char* lds = (char*)ldsv;
    char* Ah = lds;          char* Al = lds + 8192;
    char* Ih = lds + 16384;  char* Il = lds + 24576;
    char* Rh = lds + 32768;  char* Rl = lds + 40960;

    const int nb   = blockIdx.z;
    const int tid  = threadIdx.x;
    const int row0 = blockIdx.y * 128;           // batch rows
    const int col0 = blockIdx.x * 128;           // output cols within Hb

    const int sr  = tid >> 2;
    const int scb = tid & 3;
    const float* Ald = xc  + (long)(row0 + sr) * HH + nb * HB + scb * 8;
    const float* Ild = Wi  + (long)nb * HB * HB + (long)(col0 + sr) * HB + scb * 8;
    const float* Rld = Wrg + (long)nb * HB * HB + (long)(col0 + sr) * HB + scb * 8;
    const long a64 = 64L * HH;
    const long w64 = 64L * HB;

    const int lane = tid & 63;
    const int wr = (tid >> 7) & 1;
    const int wc = (tid >> 6) & 1;
    const int fm = lane & 15;
    const int kb = lane >> 4;
    const int slot = ((kb ^ ((fm >> 1) & 3)) & 3) * 16;
    const int aoff = (wr * 64 + fm) * 64 + slot;
    const int boff = (wc * 64 + fm) * 64 + slot;

    f32x4 ai[4][4] = {}, ar[4][4] = {};

    for (int kt = 0; kt < HB / BK; ++kt) {
        const int ko = kt * BK;
        const float4 a0 = *(const float4*)(Ald + ko);
        const float4 a1 = *(const float4*)(Ald + ko + 4);
        const float4 a2 = *(const float4*)(Ald + a64 + ko);
        const float4 a3 = *(const float4*)(Ald + a64 + ko + 4);
        const float4 i0 = *(const float4*)(Ild + ko);
        const float4 i1 = *(const float4*)(Ild + ko + 4);
        const float4 i2 = *(const float4*)(Ild + w64 + ko);
        const float4 i3 = *(const float4*)(Ild + w64 + ko + 4);
        const float4 r0 = *(const float4*)(Rld + ko);
        const float4 r1 = *(const float4*)(Rld + ko + 4);
        const float4 r2 = *(const float4*)(Rld + w64 + ko);
        const float4 r3 = *(const float4*)(Rld + w64 + ko + 4);
        __syncthreads();                          // prev tile fully read
        cvt_store(Ah, Al, sr,      scb, a0, a1);
        cvt_store(Ah, Al, sr + 64, scb, a2, a3);
        cvt_store(Ih, Il, sr,      scb, i0, i1);
        cvt_store(Ih, Il, sr + 64, scb, i2, i3);
        cvt_store(Rh, Rl, sr,      scb, r0, r1);
        cvt_store(Rh, Rl, sr + 64, scb, r2, r3);
        __syncthreads();
        bh8 ahf[4], alf[4];
        #pragma unroll
        for (int i = 0; i < 4; ++i) {
            ahf[i] = *(const bh8*)(Ah + aoff + i * 1024);
            alf[i] = *(const bh8*)(Al + aoff + i * 1024);
        }
        #pragma unroll
        for (int j = 0; j < 4; ++j) {
            const bh8 bihf = *(const bh8*)(Ih + boff + j * 1024);
            const bh8 bilf = *(const bh8*)(Il + boff + j * 1024);
            const bh8 brhf = *(const bh8*)(Rh + boff + j * 1024);
            const bh8 brlf = *(const bh8*)(Rl + boff + j * 1024);
            #pragma unroll
            for (int i = 0; i < 4; ++i)
                ai[i][j] = __builtin_amdgcn_mfma_f32_16x16x32_bf16(ahf[i], bihf, ai[i][j], 0, 0, 0);
            #pragma unroll
            for (int i = 0; i < 4; ++i)
                ai[i][j] = __builtin_amdgcn_mfma_f32_16x16x32_bf16(ahf[i], bilf, ai[i][j], 0, 0, 0);
            #pragma unroll
            for (int i = 0; i < 4; ++i)
                ai[i][j] = __builtin_amdgcn_mfma_f32_16x16x32_bf16(alf[i], bihf, ai[i][j], 0, 0, 0);
            #pragma unroll
            for (int i = 0; i < 4; ++i)
                ar[i][j] = __builtin_amdgcn_mfma_f32_16x16x32_bf16(ahf[i], brhf, ar[i][j], 0, 0, 0);
            #pragma unroll
            for (int i = 0; i < 4; ++i)
                ar[i][j] = __builtin_amdgcn_mfma_f32_16x16x32_bf16(ahf[i], brlf, ar[i][j], 0, 0, 0);
            #pragma unroll
            for (int i = 0; i < 4; ++i)
                ar[i][j] = __builtin_amdgcn_mfma_f32_16x16x32_bf16(alf[i], brhf, ar[i][j], 0, 0, 0);
        }
    }

    // RG-LRU epilogue (verified elementwise math from rglru_kernel)
    const int erow = row0 + wr * 64 + (lane >> 4) * 4;
    const int ecolL = col0 + wc * 64 + fm;
    #pragma unroll
    for (int j = 0; j < 4; ++j) {
        const int gcol = nb * HB + ecolL + j * 16;
        const float la8 = 8.0f * logf(av[gcol]);
        #pragma unroll
        for (int i = 0; i < 4; ++i)
            #pragma unroll
            for (int r = 0; r < 4; ++r) {
                const long off = (long)(erow + i * 16 + r) * HH + gcol;
                const float it = 1.0f / (1.0f + expf(-ai[i][j][r]));
                const float rt = 1.0f / (1.0f + expf(-ar[i][j][r]));
                const float at = expf(la8 * rt);
                const float mult = sqrtf(fmaxf(0.0f, 1.0f - at * at));
                const float o = fmaf(rg[off], at, mult * (it * xc[off]));
                nrs[off]  = o;
                hbuf[off] = gate[off] * o;
            }
    }
}

// xc = sum_k window[b,k,h]*conv_w[k,h] + conv_b[h]; also shifts conv_state.
__global__ void conv_kernel(const float* __restrict__ cs,   // [B,3,H]
                            const float* __restrict__ xr,   // [B,H]
                            const float* __restrict__ cw,   // [4,H]
                            const float* __restrict__ cb,   // [H]
                            float* __restrict__ xc,         // [B,H]
                            float* __restrict__ ncs)        // [B,3,H]
{
    const long idx = (long)blockIdx.x * blockDim.x + threadIdx.x;
    const long n4 = (long)BB * HH / 4;
    if (idx >= n4) return;
    const long b = idx / (HH / 4);
    const int  h = (int)(idx % (HH / 4)) * 4;

    const float4 c0 = *(const float4*)&cs[(b * 3 + 0) * HH + h];
    const float4 c1 = *(const float4*)&cs[(b * 3 + 1) * HH + h];
    const float4 c2 = *(const float4*)&cs[(b * 3 + 2) * HH + h];
    const float4 xv = *(const float4*)&xr[b * HH + h];
    const float4 w0 = *(const float4*)&cw[0 * HH + h];
    const float4 w1 = *(const float4*)&cw[1 * HH + h];
    const float4 w2 = *(const float4*)&cw[2 * HH + h];
    const float4 w3 = *(const float4*)&cw[3 * HH + h];
    const float4 bb = *(const float4*)&cb[h];

    float4 r;
    r.x = fmaf(c0.x, w0.x, fmaf(c1.x, w1.x, fmaf(c2.x, w2.x, fmaf(xv.x, w3.x, bb.x))));
    r.y = fmaf(c0.y, w0.y, fmaf(c1.y, w1.y, fmaf(c2.y, w2.y, fmaf(xv.y, w3.y, bb.y))));
    r.z = fmaf(c0.z, w0.z, fmaf(c1.z, w1.z, fmaf(c2.z, w2.z, fmaf(xv.z, w3.z, bb.z))));
    r.w = fmaf(c0.w, w0.w, fmaf(c1.w, w1.w, fmaf(c2.w, w2.w, fmaf(xv.w, w3.w, bb.w))));

    *(float4*)&xc[b * HH + h] = r;
    *(float4*)&ncs[(b * 3 + 0) * HH + h] = c1;
    *(float4*)&ncs[(b * 3 + 1) * HH + h] = c2;
    *(float4*)&ncs[(b * 3 + 2) * HH + h] = xv;
}

extern "C" void kernel_launch(void* const* d_in, const int* in_sizes, int n_in,
                              void* d_out, int out_size, void* d_ws, size_t ws_size,
                              hipStream_t stream) {
    const float* x    = (const float*)d_in[0];
    const float* cs   = (const float*)d_in[1];
    const float* rg   = (const float*)d_in[2];
    const float* Wg   = (const float*)d_in[3];
    const float* Wr   = (const float*)d_in[4];
    const float* Wo   = (const float*)d_in[5];
    const float* cw   = (const float*)d_in[6];
    const float* cb   = (const float*)d_in[7];
    const float* Wi   = (const float*)d_in[8];
    const float* Wrg  = (const float*)d_in[9];
    const float* av   = (const float*)d_in[10];

    const long BH = (long)BB * HH;
    float* out = (float*)d_out;            // [B,H]
    float* ncs = out + BH;                 // [B,3,H]
    float* nrs = out + 4 * BH;             // [B,H]

    float* ws   = (float*)d_ws;
    float* gate = ws;                      // [B,H]; bd_rglru writes h here
    float* xr   = ws + BH;                 // [B,H]
    float* xc   = ws + 2 * BH;             // [B,H]

    const dim3 blk(256);
    const dim3 g1(HH / 128, BB / 128, 1);
    const dim3 g2(HB / 128, BB / 128, NBK);
    const int nElem4 = (int)(BH / 4);
    const dim3 ge((nElem4 + 255) / 256);

    // 1. gate = gelu(x @ Wg^T)
    bgemm_bt<1><<<g1, blk, 0, stream>>>(x, HH, 0, Wg, HH, 0, gate, HH, 0, HH);
    // 2. xr = x @ Wr^T
    bgemm_bt<0><<<g1, blk, 0, stream>>>(x, HH, 0, Wr, HH, 0, xr, HH, 0, HH);
    // 3. conv + state shift
    conv_kernel<<<ge, blk, 0, stream>>>(cs, xr, cw, cb, xc, ncs);
    // 4. fused blockdiag(Wi)+blockdiag(Wrg)+RG-LRU: nrs (d_out), h -> gate buf
    bd_rglru<<<g2, blk, 0, stream>>>(xc, Wi, Wrg, rg, gate, av, nrs, gate);
    // 5. out = h @ Wo^T
    bgemm_bt<0><<<g1, blk, 0, stream>>>(gate, HH, 0, Wo, HH, 0, out, HH, 0, HH);
}